// Round 23
// baseline (199.058 us; speedup 1.0000x reference)
//
#include <hip/hip_runtime.h>

#define BSZ 256
#define MAXA 8
#define CTXD 128
#define HID 512
#define STD 512
#define TACD 128
#define DEFN 20000
#define CVD 256
#define DIMQ 257
#define LNGW 2056   // MAX_ARGS*DIMQ

typedef __attribute__((ext_vector_type(8))) short bf16x8;
typedef __attribute__((ext_vector_type(4))) float f32x4;

// ---- ws layout ----
// int region
#define O_TOT 0
#define O_NP  1
#define O_CS  16      // ctx_start[257]
#define O_AS  288     // arg_start[257]
#define O_AB  560     // arg_batch[2048]
#define O_SL  2608    // arg_slot[2048]
#define O_PS  4656    // pair_start[2049]
// float region.  Live-interval contract (ORDER-DEPENDENT):
//  GQB/QB: extract -> gglob/pairs.  WST: head->fc1.  STB: fc1->fc2.  LNG: fc2->extract.
//  WQT: head->fc2.  QK (overlays WQT): qk -> pairs (valid AFTER fc2).
//  GKB (141312..1421312) overlays WST/STB/LNG/WQT/QK: k_gk runs after pairs (QK dead).
//  QLB (extract->qk) and WKB (head->qk) live ABOVE 1421312 — disjoint from GKB. ✓
#define F_GQB  8192      // 2048*128 ushort = 131072 fl -> 139264
#define F_QB   139264    // 2048 -> 141312
#define F_WST  141312    // 512*640 ushort = 163840 fl -> 305152
#define F_STB  305152    // 256*512 ushort = 65536 fl -> 370688
#define F_LNG  370688    // 256*2056 fp32 = 526336 fl -> 897024
#define F_WQT  897024    // 2056*512 ushort = 526336 fl -> 1423360
#define F_QK   897024    // 2048*256 fp32 (overlays dead WqT after fc2)
#define F_GKB  141312    // 20000*128 ushort -> 1421312 (live ONLY gk->gglob, after pairs)
#define F_QLB  1423360   // 2048*128 ushort = 131072 fl -> 1554432
#define F_WKB  1554432   // 256*128 ushort = 16384 fl -> 1570816  (6.28MB < 6.48MB proven)

__device__ __forceinline__ ushort f2bf(float f) {
    uint u = __float_as_uint(f);
    return (ushort)((u + 0x7FFFu + ((u >> 16) & 1u)) >> 16);
}

// ---- fused independent head work: bounds | trans(Wst) | trans(Wq) | cvt(Wkey) ----
__global__ __launch_bounds__(256) void k_head(const int* __restrict__ ctx_ids, int n_ctx,
                                              int* __restrict__ W,
                                              const float* __restrict__ Wst, ushort* __restrict__ oWst,
                                              const float* __restrict__ Wq, ushort* __restrict__ oWq,
                                              const float* __restrict__ Wkey, ushort* __restrict__ oWk) {
    __shared__ float t[32][33];
    int bx = blockIdx.x;
    int tid = threadIdx.x;
    if (bx < 512) {
        int i = bx * 256 + tid;
        if (i >= n_ctx) return;
        int cur = ctx_ids[i];
        int prev = (i == 0) ? -1 : ctx_ids[i - 1];
        for (int b = prev + 1; b <= cur; b++) W[O_CS + b] = i;
        if (i == n_ctx - 1) {
            for (int b = cur + 1; b <= BSZ; b++) W[O_CS + b] = n_ctx;
        }
        return;
    }
    if (bx >= 1872) {
        int i = (bx - 1872) * 1024 + tid * 4;
        float4 v = *(const float4*)(Wkey + i);
        ushort4 o; o.x = f2bf(v.x); o.y = f2bf(v.y); o.z = f2bf(v.z); o.w = f2bf(v.w);
        *(ushort4*)(oWk + i) = o;
        return;
    }
    const float* in; ushort* out; int R, C, tx, ty;
    if (bx < 832) { in = Wst; out = oWst; R = 640; C = 512; int b = bx - 512; tx = b & 15; ty = b >> 4; }
    else          { in = Wq;  out = oWq;  R = 512; C = 2056; int b = bx - 832; tx = b % 65; ty = b / 65; }
    int c0 = tx * 32, r0 = ty * 32;
    int lx = tid & 31, ly = tid >> 5;
    #pragma unroll
    for (int i = 0; i < 32; i += 8) {
        int r = r0 + ly + i, c = c0 + lx;
        t[ly + i][lx] = (r < R && c < C) ? in[(size_t)r * C + c] : 0.f;
    }
    __syncthreads();
    #pragma unroll
    for (int i = 0; i < 32; i += 8) {
        int oc = c0 + ly + i;
        int orr = r0 + lx;
        if (oc < C && orr < R) out[(size_t)oc * R + orr] = f2bf(t[lx][ly + i]);
    }
}

// small scans over 256 entries (reads ctx starts from W)
__global__ __launch_bounds__(256) void k_scan(const int* __restrict__ arg_cnt, int* __restrict__ W) {
    __shared__ int s_start[BSZ + 1];
    __shared__ int s_len[BSZ];
    __shared__ int s_scan[BSZ];
    __shared__ int s_as[BSZ + 1];
    __shared__ int s_ab[2048];
    __shared__ int s_sl[2048];
    __shared__ int s_ps[BSZ];
    int tid = threadIdx.x;
    s_start[tid] = W[O_CS + tid];
    if (tid == 0) s_start[BSZ] = W[O_CS + BSZ];
    int c = arg_cnt[tid];
    s_scan[tid] = c;
    __syncthreads();
    s_len[tid] = s_start[tid + 1] - s_start[tid];
    for (int off = 1; off < BSZ; off <<= 1) {
        int v = s_scan[tid];
        int a = (tid >= off) ? s_scan[tid - off] : 0;
        __syncthreads();
        s_scan[tid] = v + a;
        __syncthreads();
    }
    int astart = s_scan[tid] - c;
    s_as[tid] = astart;
    if (tid == BSZ - 1) s_as[BSZ] = s_scan[tid];
    __syncthreads();
    int total = s_as[BSZ];
    for (int k = 0; k < c; k++) { s_ab[astart + k] = tid; s_sl[astart + k] = k; }
    __syncthreads();
    int base = tid * 8;
    int loc[8]; int run = 0;
    for (int j = 0; j < 8; j++) {
        int t = base + j;
        int l = (t < total) ? s_len[s_ab[t]] : 0;
        loc[j] = run; run += l;
    }
    s_ps[tid] = run;
    __syncthreads();
    for (int off = 1; off < BSZ; off <<= 1) {
        int v = s_ps[tid];
        int a = (tid >= off) ? s_ps[tid - off] : 0;
        __syncthreads();
        s_ps[tid] = v + a;
        __syncthreads();
    }
    int pbase = s_ps[tid] - run;
    int np = s_ps[BSZ - 1];
    W[O_AS + tid] = astart;
    if (tid == 0) { W[O_AS + BSZ] = total; W[O_TOT] = total; W[O_NP] = np; W[O_PS + 2048] = np; }
    for (int j = 0; j < 8; j++) {
        int t = base + j;
        W[O_PS + t] = pbase + loc[j];
        W[O_AB + t] = (t < total) ? s_ab[t] : 0;
        W[O_SL + t] = (t < total) ? s_sl[t] : 0;
    }
}

__device__ __forceinline__ bf16x8 cvt8(float4 a, float4 b) {
    bf16x8 r;
    r[0] = (short)f2bf(a.x); r[1] = (short)f2bf(a.y); r[2] = (short)f2bf(a.z); r[3] = (short)f2bf(a.w);
    r[4] = (short)f2bf(b.x); r[5] = (short)f2bf(b.y); r[6] = (short)f2bf(b.z); r[7] = (short)f2bf(b.w);
    return r;
}

// stb = bf16(relu([se|te] @ W_st + b_st)).  LDS-free MFMA, 1 wave/block, 16m x 32n tile.
__global__ __launch_bounds__(64) void k_fc1(const float* __restrict__ se, const float* __restrict__ te,
                                            const ushort* __restrict__ WstT, const float* __restrict__ bias,
                                            ushort* __restrict__ stb) {
    int bid = blockIdx.x;
    int m0 = (bid >> 4) * 16, n0 = (bid & 15) * 32;
    int lane = threadIdx.x;
    int lhi = lane >> 4, llo = lane & 15;
    f32x4 acc[2] = {};
    #pragma unroll
    for (int kk = 0; kk < 20; kk++) {
        int kb = kk * 32 + lhi * 8;
        const float* xr = (kb < 512) ? se + (size_t)(m0 + llo) * 512 + kb
                                     : te + (size_t)(m0 + llo) * 128 + (kb - 512);
        float4 x0 = *(const float4*)xr;
        float4 x1 = *(const float4*)(xr + 4);
        bf16x8 bfr = cvt8(x0, x1);
        #pragma unroll
        for (int nt = 0; nt < 2; nt++) {
            bf16x8 afr = *(const bf16x8*)(WstT + (size_t)(n0 + nt * 16 + llo) * 640 + kb);
            acc[nt] = __builtin_amdgcn_mfma_f32_16x16x32_bf16(afr, bfr, acc[nt], 0, 0, 0);
        }
    }
    #pragma unroll
    for (int nt = 0; nt < 2; nt++) {
        int n = n0 + nt * 16 + lhi * 4;
        float4 bb = *(const float4*)(bias + n);
        ushort4 o;
        o.x = f2bf(fmaxf(acc[nt][0] + bb.x, 0.f));
        o.y = f2bf(fmaxf(acc[nt][1] + bb.y, 0.f));
        o.z = f2bf(fmaxf(acc[nt][2] + bb.z, 0.f));
        o.w = f2bf(fmaxf(acc[nt][3] + bb.w, 0.f));
        *(ushort4*)(stb + (size_t)(m0 + llo) * 512 + n) = o;
    }
}

// LNG = stb @ W_q + b_q (fp32 out).  LDS-free MFMA, 1 wave/block, 16m x 32n tile.
__global__ __launch_bounds__(64) void k_fc2(const ushort* __restrict__ stb, const ushort* __restrict__ WqT,
                                            const float* __restrict__ bias, float* __restrict__ LNG) {
    int n0 = blockIdx.x * 32, m0 = blockIdx.y * 16;
    int lane = threadIdx.x;
    int lhi = lane >> 4, llo = lane & 15;
    f32x4 acc[2] = {};
    #pragma unroll
    for (int kk = 0; kk < 16; kk++) {
        int kb = kk * 32 + lhi * 8;
        bf16x8 bfr = *(const bf16x8*)(stb + (size_t)(m0 + llo) * 512 + kb);
        #pragma unroll
        for (int nt = 0; nt < 2; nt++) {
            int n = n0 + nt * 16 + llo; if (n > 2055) n = 2055;
            bf16x8 afr = *(const bf16x8*)(WqT + (size_t)n * 512 + kb);
            acc[nt] = __builtin_amdgcn_mfma_f32_16x16x32_bf16(afr, bfr, acc[nt], 0, 0, 0);
        }
    }
    #pragma unroll
    for (int nt = 0; nt < 2; nt++) {
        int n = n0 + nt * 16 + lhi * 4;
        if (n < 2056) {
            float4 bb = *(const float4*)(bias + n);
            f32x4 v = {acc[nt][0] + bb.x, acc[nt][1] + bb.y, acc[nt][2] + bb.z, acc[nt][3] + bb.w};
            *(f32x4*)(LNG + (size_t)(m0 + llo) * 2056 + n) = v;
        }
    }
}

// Per active arg t: split LNG row -> GQB(bf16), QLB(bf16 local query), none-logit, QB.
__global__ __launch_bounds__(256) void k_extract(const int* __restrict__ W, const float* __restrict__ LNG,
                                                 const float* __restrict__ bkey,
                                                 ushort* __restrict__ GQB, ushort* __restrict__ QLB,
                                                 float* __restrict__ out, int L, float* __restrict__ QB) {
    int t = blockIdx.x;
    int total = W[O_TOT];
    int tid = threadIdx.x;
    if (t >= total) {
        if (tid < 128) QLB[t * 128 + tid] = 0;
        else GQB[t * 128 + tid - 128] = 0;
        return;
    }
    int b = W[O_AB + t], slot = W[O_SL + t];
    const float* base = LNG + b * LNGW + slot * DIMQ;
    __shared__ float sl[CTXD];
    if (tid < 128) {
        float v = base[tid];
        sl[tid] = v;
        QLB[t * 128 + tid] = f2bf(v);
    } else {
        int d = tid - 128;
        GQB[t * 128 + d] = f2bf(base[129 + d]);
    }
    if (tid == 0) {
        int np = W[O_NP];
        out[np + t] = (float)t;
        out[L + np + t] = base[128];
    }
    __syncthreads();
    if (tid == 0) {
        float qb = 0.f;
        for (int k = 0; k < 128; k++) qb += bkey[k] * sl[k];
        QB[t] = qb;
    }
}

// QK[2048 x 256] = QLB[2048 x 128] @ WKB^T.  LDS-free MFMA, 1 wave/block, 16t x 32v.
__global__ __launch_bounds__(64) void k_qk(const ushort* __restrict__ QLB, const ushort* __restrict__ WKB,
                                           float* __restrict__ QK) {
    int n0 = blockIdx.x * 32, m0 = blockIdx.y * 16;
    int lane = threadIdx.x;
    int lhi = lane >> 4, llo = lane & 15;
    f32x4 acc[2] = {};
    #pragma unroll
    for (int kk = 0; kk < 4; kk++) {
        int kb = kk * 32 + lhi * 8;
        bf16x8 bfr = *(const bf16x8*)(QLB + (size_t)(m0 + llo) * 128 + kb);
        #pragma unroll
        for (int nt = 0; nt < 2; nt++) {
            bf16x8 afr = *(const bf16x8*)(WKB + (size_t)(n0 + nt * 16 + llo) * 128 + kb);
            acc[nt] = __builtin_amdgcn_mfma_f32_16x16x32_bf16(afr, bfr, acc[nt], 0, 0, 0);
        }
    }
    #pragma unroll
    for (int nt = 0; nt < 2; nt++) {
        int v = n0 + nt * 16 + lhi * 4;
        *(f32x4*)(QK + (size_t)(m0 + llo) * 256 + v) = acc[nt];
    }
}

// gather + L2-normalize definition embeddings -> bf16 table in ws
// MUST launch after k_pairs (GKB overlays QK/LNG/WST/WQT — ws contract above).
__global__ __launch_bounds__(256) void k_gk(const int* __restrict__ gctx, const float* __restrict__ emb,
                                            ushort* __restrict__ gkb) {
    int tid = threadIdx.x;
    int g = blockIdx.x * 8 + (tid >> 5);
    int row = gctx[g];
    int c = tid & 31;
    float4 e = *(const float4*)(emb + (size_t)row * 128 + c * 4);
    float ss = e.x * e.x + e.y * e.y + e.z * e.z + e.w * e.w;
    #pragma unroll
    for (int off = 1; off < 32; off <<= 1) ss += __shfl_xor(ss, off);
    float sc = 1.f / (1e-7f + sqrtf(ss));
    ushort4 o;
    o.x = f2bf(e.x * sc); o.y = f2bf(e.y * sc); o.z = f2bf(e.z * sc); o.w = f2bf(e.w * sc);
    *(ushort4*)(gkb + (size_t)g * 128 + c * 4) = o;
}

// local logits: 4-lane groups, 16 rows/wave, QK staged in LDS (broadcast reads).
__global__ __launch_bounds__(256) void k_pairs(const int* __restrict__ W, const float* __restrict__ ctxv,
                                               const float* __restrict__ QK, const float* __restrict__ QB,
                                               float* __restrict__ out, int L) {
    int b = blockIdx.x >> 2, sub = blockIdx.x & 3;
    int as = W[O_AS + b];
    int cnt = W[O_AS + b + 1] - as;
    if (cnt == 0) return;
    int cs = W[O_CS + b];
    int len = W[O_CS + b + 1] - cs;
    int j0 = (len * sub) >> 2, j1 = (len * (sub + 1)) >> 2;
    __shared__ float sqk[MAXA][256];
    __shared__ float sqb[MAXA];
    __shared__ int sps[MAXA];
    int tid = threadIdx.x;
    for (int i = tid; i < cnt * 256; i += 256) sqk[i >> 8][i & 255] = QK[(as + (i >> 8)) * 256 + (i & 255)];
    if (tid < cnt) { sqb[tid] = QB[as + tid]; sps[tid] = W[O_PS + as + tid]; }
    __syncthreads();
    int wv = tid >> 6, lane = tid & 63;
    int g = lane >> 2, il = lane & 3;
    for (int jb = j0 + wv * 16; jb < j1; jb += 64) {
        int j = jb + g;
        bool ok = (j < j1);
        int row = cs + (ok ? j : j1 - 1);
        const float* xr = ctxv + (size_t)row * 256;
        float acc[MAXA] = {};
        #pragma unroll
        for (int c = 0; c < 16; c++) {
            float4 x4 = *(const float4*)(xr + c * 16 + il * 4);
            #pragma unroll
            for (int a = 0; a < MAXA; a++) {
                if (a < cnt) {
                    float4 q4 = *(const float4*)(&sqk[a][c * 16 + il * 4]);
                    acc[a] += x4.x * q4.x + x4.y * q4.y + x4.z * q4.z + x4.w * q4.w;
                }
            }
        }
        #pragma unroll
        for (int a = 0; a < MAXA; a++) {
            if (a < cnt) {
                float p = acc[a];
                p += __shfl_xor(p, 1);
                p += __shfl_xor(p, 2);
                if (il == 0 && ok) {
                    out[sps[a] + j] = (float)(as + a);
                    out[L + sps[a] + j] = p + sqb[a];
                }
            }
        }
    }
}

// global logits via bf16 MFMA.  R21: latency-hiding config.
// Block = 128 defs x 128 args (grid 157x16 ~ 2512 blocks -> ~4 blocks/CU, 2x waves in
// flight vs R15); GKB A-frags register-resident; GQB B-frags DOUBLE-buffered in regs,
// loads issued 2 chunks ahead (2x latency cover); wave-private barrier-free LDS
// epilogue (R20).  Theory: gglob is GQB-load-latency bound (reads matter: R10/R16;
// writes don't: R17; barriers don't: R20).
__global__ __launch_bounds__(256) void k_gglob(const int* __restrict__ W, const ushort* __restrict__ GQB,
                                               const ushort* __restrict__ GKB, float* __restrict__ out, int L) {
    __shared__ float tile[4][32][36];
    int total = W[O_TOT], np = W[O_NP];
    int t0 = blockIdx.y * 128;
    if (t0 >= total) return;
    float* outi = out + np + total;
    float* outv = out + L + np + total;
    int g0 = blockIdx.x * 128;
    int tid = threadIdx.x, wv = tid >> 6, lane = tid & 63;
    int lhi = lane >> 4, llo = lane & 15;
    int gw = wv * 32;
    bf16x8 afr[2][4];
    #pragma unroll
    for (int nt = 0; nt < 2; nt++) {
        int g = g0 + gw + nt * 16 + llo;
        const ushort* ap = GKB + (size_t)(g < DEFN ? g : DEFN - 1) * 128 + lhi * 8;
        #pragma unroll
        for (int kk = 0; kk < 4; kk++)
            afr[nt][kk] = *(const bf16x8*)(ap + kk * 32);
    }
    int nchunk = (total - t0 + 31) >> 5;
    if (nchunk > 4) nchunk = 4;
    // 2-deep GQB prefetch: buf[0]=chunk0, buf[1]=chunk1 (GQB zero-padded to 2048 rows,
    // t0+127 <= 2047 always, so unconditional loads are safe)
    bf16x8 bfr[2][2][4];
    #pragma unroll
    for (int pb = 0; pb < 2; pb++)
        #pragma unroll
        for (int ts = 0; ts < 2; ts++)
            #pragma unroll
            for (int kk = 0; kk < 4; kk++)
                bfr[pb][ts][kk] = *(const bf16x8*)(GQB + (size_t)(t0 + pb * 32 + ts * 16 + llo) * 128 + kk * 32 + lhi * 8);
    int rr = lane >> 3, ccl = (lane & 7) * 4;
    int gcol = g0 + gw + ccl;
    bool gok = gcol < DEFN;
    for (int tc = 0; tc < nchunk; tc++) {
        int t1 = t0 + tc * 32;
        int pb = tc & 1;
        f32x4 acc[2][2] = {};
        #pragma unroll
        for (int nt = 0; nt < 2; nt++)
            #pragma unroll
            for (int kk = 0; kk < 4; kk++)
                #pragma unroll
                for (int ts = 0; ts < 2; ts++)
                    acc[ts][nt] = __builtin_amdgcn_mfma_f32_16x16x32_bf16(afr[nt][kk], bfr[pb][ts][kk], acc[ts][nt], 0, 0, 0);
        if (tc + 2 < nchunk) {
            int t2 = t1 + 64;
            #pragma unroll
            for (int ts = 0; ts < 2; ts++)
                #pragma unroll
                for (int kk = 0; kk < 4; kk++)
                    bfr[pb][ts][kk] = *(const bf16x8*)(GQB + (size_t)(t2 + ts * 16 + llo) * 128 + kk * 32 + lhi * 8);
        }
        // wave-private LDS transpose (same-wave RAW -> lgkmcnt only, no barrier)
        #pragma unroll
        for (int nt = 0; nt < 2; nt++)
            #pragma unroll
            for (int ts = 0; ts < 2; ts++)
                *(f32x4*)&tile[wv][ts * 16 + llo][nt * 16 + lhi * 4] = acc[ts][nt];
        #pragma unroll
        for (int i = 0; i < 4; i++) {
            int r = i * 8 + rr;
            int t = t1 + r;
            if (t < total && gok) {
                size_t rb = (size_t)t * DEFN + gcol;
                *(f32x4*)(outv + rb) = *(const f32x4*)&tile[wv][r][ccl];
                float ft = (float)t;
                f32x4 fi = {ft, ft, ft, ft};
                *(f32x4*)(outi + rb) = fi;
            }
        }
    }
}

extern "C" void kernel_launch(void* const* d_in, const int* in_sizes, int n_in,
                              void* d_out, int out_size, void* d_ws, size_t ws_size,
                              hipStream_t stream) {
    const float* ctx_vals  = (const float*)d_in[0];
    const float* state_emb = (const float*)d_in[1];
    const float* tactic    = (const float*)d_in[2];
    const float* emb       = (const float*)d_in[3];
    const float* W_key     = (const float*)d_in[4];
    const float* b_key     = (const float*)d_in[5];
    const float* W_st      = (const float*)d_in[6];
    const float* b_st      = (const float*)d_in[7];
    const float* W_q       = (const float*)d_in[8];
    const float* b_q       = (const float*)d_in[9];
    const int* ctx_ids     = (const int*)d_in[10];
    const int* arg_cnt     = (const int*)d_in[11];
    const int* gctx        = (const int*)d_in[12];
    int n_ctx = in_sizes[10];
    int L = out_size / 2;
    int* W  = (int*)d_ws;
    float* F = (float*)d_ws;
    float* out = (float*)d_out;

    k_head<<<dim3(1904), dim3(256), 0, stream>>>(ctx_ids, n_ctx, W,
                                                 W_st, (ushort*)(F + F_WST),
                                                 W_q, (ushort*)(F + F_WQT),
                                                 W_key, (ushort*)(F + F_WKB));
    k_scan<<<dim3(1), dim3(256), 0, stream>>>(arg_cnt, W);
    k_fc1<<<dim3(256), dim3(64), 0, stream>>>(state_emb, tactic, (ushort*)(F + F_WST), b_st,
                                              (ushort*)(F + F_STB));
    k_fc2<<<dim3(65, 16), dim3(64), 0, stream>>>((ushort*)(F + F_STB), (ushort*)(F + F_WQT), b_q,
                                                 F + F_LNG);
    k_extract<<<dim3(2048), dim3(256), 0, stream>>>(W, F + F_LNG, b_key,
                                                    (ushort*)(F + F_GQB), (ushort*)(F + F_QLB),
                                                    out, L, F + F_QB);
    k_qk<<<dim3(8, 128), dim3(64), 0, stream>>>((ushort*)(F + F_QLB), (ushort*)(F + F_WKB), F + F_QK);
    k_pairs<<<dim3(1024), dim3(256), 0, stream>>>(W, ctx_vals, F + F_QK, F + F_QB, out, L);
    k_gk<<<dim3(2500), dim3(256), 0, stream>>>(gctx, emb, (ushort*)(F + F_GKB));
    k_gglob<<<dim3(157, 16), dim3(256), 0, stream>>>(W, (ushort*)(F + F_GQB), (ushort*)(F + F_GKB), out, L);
}

// Round 24
// 143.720 us; speedup vs baseline: 1.3850x; 1.3850x over previous
//
#include <hip/hip_runtime.h>

#define BSZ 256
#define MAXA 8
#define CTXD 128
#define HID 512
#define STD 512
#define TACD 128
#define DEFN 20000
#define CVD 256
#define DIMQ 257
#define LNGW 2056   // MAX_ARGS*DIMQ

typedef __attribute__((ext_vector_type(8))) short bf16x8;
typedef __attribute__((ext_vector_type(4))) float f32x4;

// ---- ws layout ----
// int region
#define O_TOT 0
#define O_NP  1
#define O_CS  16      // ctx_start[257]
#define O_AS  288     // arg_start[257]
#define O_AB  560     // arg_batch[2048]
#define O_SL  2608    // arg_slot[2048]
#define O_PS  4656    // pair_start[2049]
// float region.  Live-interval contract (ORDER-DEPENDENT):
//  GQB/QB: extract -> gglob/pairs.  WST: head->fc1.  STB: fc1->fc2.  LNG: fc2->extract.
//  WQT: head->fc2.  QK (overlays WQT): qk -> pairs (valid AFTER fc2).
//  GKB (141312..1421312) overlays WST/STB/LNG/WQT/QK: k_gk runs after pairs (QK dead).
//  QLB (extract->qk) and WKB (head->qk) live ABOVE 1421312 — disjoint from GKB. ✓
#define F_GQB  8192      // 2048*128 ushort = 131072 fl -> 139264
#define F_QB   139264    // 2048 -> 141312
#define F_WST  141312    // 512*640 ushort = 163840 fl -> 305152
#define F_STB  305152    // 256*512 ushort = 65536 fl -> 370688
#define F_LNG  370688    // 256*2056 fp32 = 526336 fl -> 897024
#define F_WQT  897024    // 2056*512 ushort = 526336 fl -> 1423360
#define F_QK   897024    // 2048*256 fp32 (overlays dead WqT after fc2)
#define F_GKB  141312    // 20000*128 ushort -> 1421312 (live ONLY gk->gglob, after pairs)
#define F_QLB  1423360   // 2048*128 ushort = 131072 fl -> 1554432
#define F_WKB  1554432   // 256*128 ushort = 16384 fl -> 1570816  (6.28MB < 6.48MB proven)

__device__ __forceinline__ ushort f2bf(float f) {
    uint u = __float_as_uint(f);
    return (ushort)((u + 0x7FFFu + ((u >> 16) & 1u)) >> 16);
}

// ---- fused independent head work: bounds | trans(Wst) | trans(Wq) | cvt(Wkey) ----
__global__ __launch_bounds__(256) void k_head(const int* __restrict__ ctx_ids, int n_ctx,
                                              int* __restrict__ W,
                                              const float* __restrict__ Wst, ushort* __restrict__ oWst,
                                              const float* __restrict__ Wq, ushort* __restrict__ oWq,
                                              const float* __restrict__ Wkey, ushort* __restrict__ oWk) {
    __shared__ float t[32][33];
    int bx = blockIdx.x;
    int tid = threadIdx.x;
    if (bx < 512) {
        int i = bx * 256 + tid;
        if (i >= n_ctx) return;
        int cur = ctx_ids[i];
        int prev = (i == 0) ? -1 : ctx_ids[i - 1];
        for (int b = prev + 1; b <= cur; b++) W[O_CS + b] = i;
        if (i == n_ctx - 1) {
            for (int b = cur + 1; b <= BSZ; b++) W[O_CS + b] = n_ctx;
        }
        return;
    }
    if (bx >= 1872) {
        int i = (bx - 1872) * 1024 + tid * 4;
        float4 v = *(const float4*)(Wkey + i);
        ushort4 o; o.x = f2bf(v.x); o.y = f2bf(v.y); o.z = f2bf(v.z); o.w = f2bf(v.w);
        *(ushort4*)(oWk + i) = o;
        return;
    }
    const float* in; ushort* out; int R, C, tx, ty;
    if (bx < 832) { in = Wst; out = oWst; R = 640; C = 512; int b = bx - 512; tx = b & 15; ty = b >> 4; }
    else          { in = Wq;  out = oWq;  R = 512; C = 2056; int b = bx - 832; tx = b % 65; ty = b / 65; }
    int c0 = tx * 32, r0 = ty * 32;
    int lx = tid & 31, ly = tid >> 5;
    #pragma unroll
    for (int i = 0; i < 32; i += 8) {
        int r = r0 + ly + i, c = c0 + lx;
        t[ly + i][lx] = (r < R && c < C) ? in[(size_t)r * C + c] : 0.f;
    }
    __syncthreads();
    #pragma unroll
    for (int i = 0; i < 32; i += 8) {
        int oc = c0 + ly + i;
        int orr = r0 + lx;
        if (oc < C && orr < R) out[(size_t)oc * R + orr] = f2bf(t[lx][ly + i]);
    }
}

// small scans over 256 entries (reads ctx starts from W)
__global__ __launch_bounds__(256) void k_scan(const int* __restrict__ arg_cnt, int* __restrict__ W) {
    __shared__ int s_start[BSZ + 1];
    __shared__ int s_len[BSZ];
    __shared__ int s_scan[BSZ];
    __shared__ int s_as[BSZ + 1];
    __shared__ int s_ab[2048];
    __shared__ int s_sl[2048];
    __shared__ int s_ps[BSZ];
    int tid = threadIdx.x;
    s_start[tid] = W[O_CS + tid];
    if (tid == 0) s_start[BSZ] = W[O_CS + BSZ];
    int c = arg_cnt[tid];
    s_scan[tid] = c;
    __syncthreads();
    s_len[tid] = s_start[tid + 1] - s_start[tid];
    for (int off = 1; off < BSZ; off <<= 1) {
        int v = s_scan[tid];
        int a = (tid >= off) ? s_scan[tid - off] : 0;
        __syncthreads();
        s_scan[tid] = v + a;
        __syncthreads();
    }
    int astart = s_scan[tid] - c;
    s_as[tid] = astart;
    if (tid == BSZ - 1) s_as[BSZ] = s_scan[tid];
    __syncthreads();
    int total = s_as[BSZ];
    for (int k = 0; k < c; k++) { s_ab[astart + k] = tid; s_sl[astart + k] = k; }
    __syncthreads();
    int base = tid * 8;
    int loc[8]; int run = 0;
    for (int j = 0; j < 8; j++) {
        int t = base + j;
        int l = (t < total) ? s_len[s_ab[t]] : 0;
        loc[j] = run; run += l;
    }
    s_ps[tid] = run;
    __syncthreads();
    for (int off = 1; off < BSZ; off <<= 1) {
        int v = s_ps[tid];
        int a = (tid >= off) ? s_ps[tid - off] : 0;
        __syncthreads();
        s_ps[tid] = v + a;
        __syncthreads();
    }
    int pbase = s_ps[tid] - run;
    int np = s_ps[BSZ - 1];
    W[O_AS + tid] = astart;
    if (tid == 0) { W[O_AS + BSZ] = total; W[O_TOT] = total; W[O_NP] = np; W[O_PS + 2048] = np; }
    for (int j = 0; j < 8; j++) {
        int t = base + j;
        W[O_PS + t] = pbase + loc[j];
        W[O_AB + t] = (t < total) ? s_ab[t] : 0;
        W[O_SL + t] = (t < total) ? s_sl[t] : 0;
    }
}

__device__ __forceinline__ bf16x8 cvt8(float4 a, float4 b) {
    bf16x8 r;
    r[0] = (short)f2bf(a.x); r[1] = (short)f2bf(a.y); r[2] = (short)f2bf(a.z); r[3] = (short)f2bf(a.w);
    r[4] = (short)f2bf(b.x); r[5] = (short)f2bf(b.y); r[6] = (short)f2bf(b.z); r[7] = (short)f2bf(b.w);
    return r;
}

// stb = bf16(relu([se|te] @ W_st + b_st)).  LDS-free MFMA, 1 wave/block, 16m x 32n tile.
__global__ __launch_bounds__(64) void k_fc1(const float* __restrict__ se, const float* __restrict__ te,
                                            const ushort* __restrict__ WstT, const float* __restrict__ bias,
                                            ushort* __restrict__ stb) {
    int bid = blockIdx.x;
    int m0 = (bid >> 4) * 16, n0 = (bid & 15) * 32;
    int lane = threadIdx.x;
    int lhi = lane >> 4, llo = lane & 15;
    f32x4 acc[2] = {};
    #pragma unroll
    for (int kk = 0; kk < 20; kk++) {
        int kb = kk * 32 + lhi * 8;
        const float* xr = (kb < 512) ? se + (size_t)(m0 + llo) * 512 + kb
                                     : te + (size_t)(m0 + llo) * 128 + (kb - 512);
        float4 x0 = *(const float4*)xr;
        float4 x1 = *(const float4*)(xr + 4);
        bf16x8 bfr = cvt8(x0, x1);
        #pragma unroll
        for (int nt = 0; nt < 2; nt++) {
            bf16x8 afr = *(const bf16x8*)(WstT + (size_t)(n0 + nt * 16 + llo) * 640 + kb);
            acc[nt] = __builtin_amdgcn_mfma_f32_16x16x32_bf16(afr, bfr, acc[nt], 0, 0, 0);
        }
    }
    #pragma unroll
    for (int nt = 0; nt < 2; nt++) {
        int n = n0 + nt * 16 + lhi * 4;
        float4 bb = *(const float4*)(bias + n);
        ushort4 o;
        o.x = f2bf(fmaxf(acc[nt][0] + bb.x, 0.f));
        o.y = f2bf(fmaxf(acc[nt][1] + bb.y, 0.f));
        o.z = f2bf(fmaxf(acc[nt][2] + bb.z, 0.f));
        o.w = f2bf(fmaxf(acc[nt][3] + bb.w, 0.f));
        *(ushort4*)(stb + (size_t)(m0 + llo) * 512 + n) = o;
    }
}

// LNG = stb @ W_q + b_q (fp32 out).  LDS-free MFMA, 1 wave/block, 16m x 32n tile.
__global__ __launch_bounds__(64) void k_fc2(const ushort* __restrict__ stb, const ushort* __restrict__ WqT,
                                            const float* __restrict__ bias, float* __restrict__ LNG) {
    int n0 = blockIdx.x * 32, m0 = blockIdx.y * 16;
    int lane = threadIdx.x;
    int lhi = lane >> 4, llo = lane & 15;
    f32x4 acc[2] = {};
    #pragma unroll
    for (int kk = 0; kk < 16; kk++) {
        int kb = kk * 32 + lhi * 8;
        bf16x8 bfr = *(const bf16x8*)(stb + (size_t)(m0 + llo) * 512 + kb);
        #pragma unroll
        for (int nt = 0; nt < 2; nt++) {
            int n = n0 + nt * 16 + llo; if (n > 2055) n = 2055;
            bf16x8 afr = *(const bf16x8*)(WqT + (size_t)n * 512 + kb);
            acc[nt] = __builtin_amdgcn_mfma_f32_16x16x32_bf16(afr, bfr, acc[nt], 0, 0, 0);
        }
    }
    #pragma unroll
    for (int nt = 0; nt < 2; nt++) {
        int n = n0 + nt * 16 + lhi * 4;
        if (n < 2056) {
            float4 bb = *(const float4*)(bias + n);
            f32x4 v = {acc[nt][0] + bb.x, acc[nt][1] + bb.y, acc[nt][2] + bb.z, acc[nt][3] + bb.w};
            *(f32x4*)(LNG + (size_t)(m0 + llo) * 2056 + n) = v;
        }
    }
}

// Per active arg t: split LNG row -> GQB(bf16), QLB(bf16 local query), none-logit, QB.
__global__ __launch_bounds__(256) void k_extract(const int* __restrict__ W, const float* __restrict__ LNG,
                                                 const float* __restrict__ bkey,
                                                 ushort* __restrict__ GQB, ushort* __restrict__ QLB,
                                                 float* __restrict__ out, int L, float* __restrict__ QB) {
    int t = blockIdx.x;
    int total = W[O_TOT];
    int tid = threadIdx.x;
    if (t >= total) {
        if (tid < 128) QLB[t * 128 + tid] = 0;
        else GQB[t * 128 + tid - 128] = 0;
        return;
    }
    int b = W[O_AB + t], slot = W[O_SL + t];
    const float* base = LNG + b * LNGW + slot * DIMQ;
    __shared__ float sl[CTXD];
    if (tid < 128) {
        float v = base[tid];
        sl[tid] = v;
        QLB[t * 128 + tid] = f2bf(v);
    } else {
        int d = tid - 128;
        GQB[t * 128 + d] = f2bf(base[129 + d]);
    }
    if (tid == 0) {
        int np = W[O_NP];
        out[np + t] = (float)t;
        out[L + np + t] = base[128];
    }
    __syncthreads();
    if (tid == 0) {
        float qb = 0.f;
        for (int k = 0; k < 128; k++) qb += bkey[k] * sl[k];
        QB[t] = qb;
    }
}

// QK[2048 x 256] = QLB[2048 x 128] @ WKB^T.  LDS-free MFMA, 1 wave/block, 16t x 32v.
__global__ __launch_bounds__(64) void k_qk(const ushort* __restrict__ QLB, const ushort* __restrict__ WKB,
                                           float* __restrict__ QK) {
    int n0 = blockIdx.x * 32, m0 = blockIdx.y * 16;
    int lane = threadIdx.x;
    int lhi = lane >> 4, llo = lane & 15;
    f32x4 acc[2] = {};
    #pragma unroll
    for (int kk = 0; kk < 4; kk++) {
        int kb = kk * 32 + lhi * 8;
        bf16x8 bfr = *(const bf16x8*)(QLB + (size_t)(m0 + llo) * 128 + kb);
        #pragma unroll
        for (int nt = 0; nt < 2; nt++) {
            bf16x8 afr = *(const bf16x8*)(WKB + (size_t)(n0 + nt * 16 + llo) * 128 + kb);
            acc[nt] = __builtin_amdgcn_mfma_f32_16x16x32_bf16(afr, bfr, acc[nt], 0, 0, 0);
        }
    }
    #pragma unroll
    for (int nt = 0; nt < 2; nt++) {
        int v = n0 + nt * 16 + lhi * 4;
        *(f32x4*)(QK + (size_t)(m0 + llo) * 256 + v) = acc[nt];
    }
}

// gather + L2-normalize definition embeddings -> bf16 table in ws
// MUST launch after k_pairs (GKB overlays QK/LNG/WST/WQT — ws contract above).
__global__ __launch_bounds__(256) void k_gk(const int* __restrict__ gctx, const float* __restrict__ emb,
                                            ushort* __restrict__ gkb) {
    int tid = threadIdx.x;
    int g = blockIdx.x * 8 + (tid >> 5);
    int row = gctx[g];
    int c = tid & 31;
    float4 e = *(const float4*)(emb + (size_t)row * 128 + c * 4);
    float ss = e.x * e.x + e.y * e.y + e.z * e.z + e.w * e.w;
    #pragma unroll
    for (int off = 1; off < 32; off <<= 1) ss += __shfl_xor(ss, off);
    float sc = 1.f / (1e-7f + sqrtf(ss));
    ushort4 o;
    o.x = f2bf(e.x * sc); o.y = f2bf(e.y * sc); o.z = f2bf(e.z * sc); o.w = f2bf(e.w * sc);
    *(ushort4*)(gkb + (size_t)g * 128 + c * 4) = o;
}

// local logits: 4-lane groups, 16 rows/wave, QK staged in LDS (broadcast reads).
__global__ __launch_bounds__(256) void k_pairs(const int* __restrict__ W, const float* __restrict__ ctxv,
                                               const float* __restrict__ QK, const float* __restrict__ QB,
                                               float* __restrict__ out, int L) {
    int b = blockIdx.x >> 2, sub = blockIdx.x & 3;
    int as = W[O_AS + b];
    int cnt = W[O_AS + b + 1] - as;
    if (cnt == 0) return;
    int cs = W[O_CS + b];
    int len = W[O_CS + b + 1] - cs;
    int j0 = (len * sub) >> 2, j1 = (len * (sub + 1)) >> 2;
    __shared__ float sqk[MAXA][256];
    __shared__ float sqb[MAXA];
    __shared__ int sps[MAXA];
    int tid = threadIdx.x;
    for (int i = tid; i < cnt * 256; i += 256) sqk[i >> 8][i & 255] = QK[(as + (i >> 8)) * 256 + (i & 255)];
    if (tid < cnt) { sqb[tid] = QB[as + tid]; sps[tid] = W[O_PS + as + tid]; }
    __syncthreads();
    int wv = tid >> 6, lane = tid & 63;
    int g = lane >> 2, il = lane & 3;
    for (int jb = j0 + wv * 16; jb < j1; jb += 64) {
        int j = jb + g;
        bool ok = (j < j1);
        int row = cs + (ok ? j : j1 - 1);
        const float* xr = ctxv + (size_t)row * 256;
        float acc[MAXA] = {};
        #pragma unroll
        for (int c = 0; c < 16; c++) {
            float4 x4 = *(const float4*)(xr + c * 16 + il * 4);
            #pragma unroll
            for (int a = 0; a < MAXA; a++) {
                if (a < cnt) {
                    float4 q4 = *(const float4*)(&sqk[a][c * 16 + il * 4]);
                    acc[a] += x4.x * q4.x + x4.y * q4.y + x4.z * q4.z + x4.w * q4.w;
                }
            }
        }
        #pragma unroll
        for (int a = 0; a < MAXA; a++) {
            if (a < cnt) {
                float p = acc[a];
                p += __shfl_xor(p, 1);
                p += __shfl_xor(p, 2);
                if (il == 0 && ok) {
                    out[sps[a] + j] = (float)(as + a);
                    out[L + sps[a] + j] = p + sqb[a];
                }
            }
        }
    }
}

// global logits via bf16 MFMA (R12/R15 dbuf structure), y-tile = 512 args (R22).
// GKB HBM re-reads scale with y-tile count (measured: 8 tiles -> 39MB, 16 -> 97MB);
// 4 y-tiles -> ~20MB.  Block = 128 defs x 512 args, 4 waves x 32 defs; GKB A-frags
// register-resident; GQB B-frags prefetched one 32-arg chunk ahead; double-buffered
// LDS epilogue, one barrier per chunk, 512B-contiguous stores for both planes.
__global__ __launch_bounds__(256) void k_gglob(const int* __restrict__ W, const ushort* __restrict__ GQB,
                                               const ushort* __restrict__ GKB, float* __restrict__ out, int L) {
    __shared__ float tile[2][32][132];
    int total = W[O_TOT], np = W[O_NP];
    int t0 = blockIdx.y * 512;
    if (t0 >= total) return;
    float* outi = out + np + total;
    float* outv = out + L + np + total;
    int g0 = blockIdx.x * 128;
    int tid = threadIdx.x, wv = tid >> 6, lane = tid & 63;
    int lhi = lane >> 4, llo = lane & 15;
    int gw = wv * 32;
    bf16x8 afr[2][4];
    #pragma unroll
    for (int nt = 0; nt < 2; nt++) {
        int g = g0 + gw + nt * 16 + llo;
        const ushort* ap = GKB + (size_t)(g < DEFN ? g : DEFN - 1) * 128 + lhi * 8;
        #pragma unroll
        for (int kk = 0; kk < 4; kk++)
            afr[nt][kk] = *(const bf16x8*)(ap + kk * 32);
    }
    int nchunk = (total - t0 + 31) >> 5;
    if (nchunk > 16) nchunk = 16;
    bf16x8 bfr[2][4];
    #pragma unroll
    for (int ts = 0; ts < 2; ts++)
        #pragma unroll
        for (int kk = 0; kk < 4; kk++)
            bfr[ts][kk] = *(const bf16x8*)(GQB + (size_t)(t0 + ts * 16 + llo) * 128 + kk * 32 + lhi * 8);
    int half = lane >> 5, cc = (lane & 31) * 4;
    bool gok = (g0 + cc) < DEFN;
    for (int tc = 0; tc < nchunk; tc++) {
        int t1 = t0 + tc * 32;
        int buf = tc & 1;
        f32x4 acc[2][2] = {};
        #pragma unroll
        for (int nt = 0; nt < 2; nt++)
            #pragma unroll
            for (int kk = 0; kk < 4; kk++)
                #pragma unroll
                for (int ts = 0; ts < 2; ts++)
                    acc[ts][nt] = __builtin_amdgcn_mfma_f32_16x16x32_bf16(afr[nt][kk], bfr[ts][kk], acc[ts][nt], 0, 0, 0);
        if (tc + 1 < nchunk) {
            int t2 = t1 + 32;
            #pragma unroll
            for (int ts = 0; ts < 2; ts++)
                #pragma unroll
                for (int kk = 0; kk < 4; kk++)
                    bfr[ts][kk] = *(const bf16x8*)(GQB + (size_t)(t2 + ts * 16 + llo) * 128 + kk * 32 + lhi * 8);
        }
        #pragma unroll
        for (int nt = 0; nt < 2; nt++)
            #pragma unroll
            for (int ts = 0; ts < 2; ts++)
                *(f32x4*)&tile[buf][ts * 16 + llo][gw + nt * 16 + lhi * 4] = acc[ts][nt];
        __syncthreads();
        #pragma unroll
        for (int rp = 0; rp < 4; rp++) {
            int r = wv * 8 + rp * 2 + half;
            int t = t1 + r;
            if (t < total && gok) {
                size_t rb = (size_t)t * DEFN + g0 + cc;
                *(f32x4*)(outv + rb) = *(const f32x4*)&tile[buf][r][cc];
                float ft = (float)t;
                f32x4 fi = {ft, ft, ft, ft};
                *(f32x4*)(outi + rb) = fi;
            }
        }
    }
}

extern "C" void kernel_launch(void* const* d_in, const int* in_sizes, int n_in,
                              void* d_out, int out_size, void* d_ws, size_t ws_size,
                              hipStream_t stream) {
    const float* ctx_vals  = (const float*)d_in[0];
    const float* state_emb = (const float*)d_in[1];
    const float* tactic    = (const float*)d_in[2];
    const float* emb       = (const float*)d_in[3];
    const float* W_key     = (const float*)d_in[4];
    const float* b_key     = (const float*)d_in[5];
    const float* W_st      = (const float*)d_in[6];
    const float* b_st      = (const float*)d_in[7];
    const float* W_q       = (const float*)d_in[8];
    const float* b_q       = (const float*)d_in[9];
    const int* ctx_ids     = (const int*)d_in[10];
    const int* arg_cnt     = (const int*)d_in[11];
    const int* gctx        = (const int*)d_in[12];
    int n_ctx = in_sizes[10];
    int L = out_size / 2;
    int* W  = (int*)d_ws;
    float* F = (float*)d_ws;
    float* out = (float*)d_out;

    k_head<<<dim3(1904), dim3(256), 0, stream>>>(ctx_ids, n_ctx, W,
                                                 W_st, (ushort*)(F + F_WST),
                                                 W_q, (ushort*)(F + F_WQT),
                                                 W_key, (ushort*)(F + F_WKB));
    k_scan<<<dim3(1), dim3(256), 0, stream>>>(arg_cnt, W);
    k_fc1<<<dim3(256), dim3(64), 0, stream>>>(state_emb, tactic, (ushort*)(F + F_WST), b_st,
                                              (ushort*)(F + F_STB));
    k_fc2<<<dim3(65, 16), dim3(64), 0, stream>>>((ushort*)(F + F_STB), (ushort*)(F + F_WQT), b_q,
                                                 F + F_LNG);
    k_extract<<<dim3(2048), dim3(256), 0, stream>>>(W, F + F_LNG, b_key,
                                                    (ushort*)(F + F_GQB), (ushort*)(F + F_QLB),
                                                    out, L, F + F_QB);
    k_qk<<<dim3(8, 128), dim3(64), 0, stream>>>((ushort*)(F + F_QLB), (ushort*)(F + F_WKB), F + F_QK);
    k_pairs<<<dim3(1024), dim3(256), 0, stream>>>(W, ctx_vals, F + F_QK, F + F_QB, out, L);
    k_gk<<<dim3(2500), dim3(256), 0, stream>>>(gctx, emb, (ushort*)(F + F_GKB));
    k_gglob<<<dim3(157, 4), dim3(256), 0, stream>>>(W, (ushort*)(F + F_GQB), (ushort*)(F + F_GKB), out, L);
}

// Round 25
// 136.724 us; speedup vs baseline: 1.4559x; 1.0512x over previous
//
#include <hip/hip_runtime.h>

#define BSZ 256
#define MAXA 8
#define CTXD 128
#define HID 512
#define STD 512
#define TACD 128
#define DEFN 20000
#define CVD 256
#define DIMQ 257
#define LNGW 2056   // MAX_ARGS*DIMQ

typedef __attribute__((ext_vector_type(8))) short bf16x8;
typedef __attribute__((ext_vector_type(4))) float f32x4;

// ---- ws layout ----
// int region
#define O_TOT 0
#define O_NP  1
#define O_CS  16      // ctx_start[257]
#define O_AS  288     // arg_start[257]
#define O_AB  560     // arg_batch[2048]
#define O_SL  2608    // arg_slot[2048]
#define O_PS  4656    // pair_start[2049]
// float region.  Live-interval contract (ORDER-DEPENDENT):
//  GQB/QB: extract -> gglob/pairs.  WST: head->fc1.  STB: fc1->fc2.  LNG: fc2->extract.
//  WQT: head->fc2.  QK (overlays WQT): qk -> pairs (valid AFTER fc2).
//  GKB (141312..1421312) overlays WST/STB/LNG/WQT/QK: k_gk runs after pairs (QK dead).
//  QLB (extract->qk) and WKB (head->qk) live ABOVE 1421312 — disjoint from GKB. ✓
#define F_GQB  8192      // 2048*128 ushort = 131072 fl -> 139264
#define F_QB   139264    // 2048 -> 141312
#define F_WST  141312    // 512*640 ushort = 163840 fl -> 305152
#define F_STB  305152    // 256*512 ushort = 65536 fl -> 370688
#define F_LNG  370688    // 256*2056 fp32 = 526336 fl -> 897024
#define F_WQT  897024    // 2056*512 ushort = 526336 fl -> 1423360
#define F_QK   897024    // 2048*256 fp32 (overlays dead WqT after fc2)
#define F_GKB  141312    // 20000*128 ushort -> 1421312 (live ONLY gk->gglob, after pairs)
#define F_QLB  1423360   // 2048*128 ushort = 131072 fl -> 1554432
#define F_WKB  1554432   // 256*128 ushort = 16384 fl -> 1570816  (6.28MB < 6.48MB proven)

__device__ __forceinline__ ushort f2bf(float f) {
    uint u = __float_as_uint(f);
    return (ushort)((u + 0x7FFFu + ((u >> 16) & 1u)) >> 16);
}

// ---- fused independent head work: bounds | trans(Wst) | trans(Wq) | cvt(Wkey) ----
__global__ __launch_bounds__(256) void k_head(const int* __restrict__ ctx_ids, int n_ctx,
                                              int* __restrict__ W,
                                              const float* __restrict__ Wst, ushort* __restrict__ oWst,
                                              const float* __restrict__ Wq, ushort* __restrict__ oWq,
                                              const float* __restrict__ Wkey, ushort* __restrict__ oWk) {
    __shared__ float t[32][33];
    int bx = blockIdx.x;
    int tid = threadIdx.x;
    if (bx < 512) {
        int i = bx * 256 + tid;
        if (i >= n_ctx) return;
        int cur = ctx_ids[i];
        int prev = (i == 0) ? -1 : ctx_ids[i - 1];
        for (int b = prev + 1; b <= cur; b++) W[O_CS + b] = i;
        if (i == n_ctx - 1) {
            for (int b = cur + 1; b <= BSZ; b++) W[O_CS + b] = n_ctx;
        }
        return;
    }
    if (bx >= 1872) {
        int i = (bx - 1872) * 1024 + tid * 4;
        float4 v = *(const float4*)(Wkey + i);
        ushort4 o; o.x = f2bf(v.x); o.y = f2bf(v.y); o.z = f2bf(v.z); o.w = f2bf(v.w);
        *(ushort4*)(oWk + i) = o;
        return;
    }
    const float* in; ushort* out; int R, C, tx, ty;
    if (bx < 832) { in = Wst; out = oWst; R = 640; C = 512; int b = bx - 512; tx = b & 15; ty = b >> 4; }
    else          { in = Wq;  out = oWq;  R = 512; C = 2056; int b = bx - 832; tx = b % 65; ty = b / 65; }
    int c0 = tx * 32, r0 = ty * 32;
    int lx = tid & 31, ly = tid >> 5;
    #pragma unroll
    for (int i = 0; i < 32; i += 8) {
        int r = r0 + ly + i, c = c0 + lx;
        t[ly + i][lx] = (r < R && c < C) ? in[(size_t)r * C + c] : 0.f;
    }
    __syncthreads();
    #pragma unroll
    for (int i = 0; i < 32; i += 8) {
        int oc = c0 + ly + i;
        int orr = r0 + lx;
        if (oc < C && orr < R) out[(size_t)oc * R + orr] = f2bf(t[lx][ly + i]);
    }
}

// small scans over 256 entries (reads ctx starts from W)
__global__ __launch_bounds__(256) void k_scan(const int* __restrict__ arg_cnt, int* __restrict__ W) {
    __shared__ int s_start[BSZ + 1];
    __shared__ int s_len[BSZ];
    __shared__ int s_scan[BSZ];
    __shared__ int s_as[BSZ + 1];
    __shared__ int s_ab[2048];
    __shared__ int s_sl[2048];
    __shared__ int s_ps[BSZ];
    int tid = threadIdx.x;
    s_start[tid] = W[O_CS + tid];
    if (tid == 0) s_start[BSZ] = W[O_CS + BSZ];
    int c = arg_cnt[tid];
    s_scan[tid] = c;
    __syncthreads();
    s_len[tid] = s_start[tid + 1] - s_start[tid];
    for (int off = 1; off < BSZ; off <<= 1) {
        int v = s_scan[tid];
        int a = (tid >= off) ? s_scan[tid - off] : 0;
        __syncthreads();
        s_scan[tid] = v + a;
        __syncthreads();
    }
    int astart = s_scan[tid] - c;
    s_as[tid] = astart;
    if (tid == BSZ - 1) s_as[BSZ] = s_scan[tid];
    __syncthreads();
    int total = s_as[BSZ];
    for (int k = 0; k < c; k++) { s_ab[astart + k] = tid; s_sl[astart + k] = k; }
    __syncthreads();
    int base = tid * 8;
    int loc[8]; int run = 0;
    for (int j = 0; j < 8; j++) {
        int t = base + j;
        int l = (t < total) ? s_len[s_ab[t]] : 0;
        loc[j] = run; run += l;
    }
    s_ps[tid] = run;
    __syncthreads();
    for (int off = 1; off < BSZ; off <<= 1) {
        int v = s_ps[tid];
        int a = (tid >= off) ? s_ps[tid - off] : 0;
        __syncthreads();
        s_ps[tid] = v + a;
        __syncthreads();
    }
    int pbase = s_ps[tid] - run;
    int np = s_ps[BSZ - 1];
    W[O_AS + tid] = astart;
    if (tid == 0) { W[O_AS + BSZ] = total; W[O_TOT] = total; W[O_NP] = np; W[O_PS + 2048] = np; }
    for (int j = 0; j < 8; j++) {
        int t = base + j;
        W[O_PS + t] = pbase + loc[j];
        W[O_AB + t] = (t < total) ? s_ab[t] : 0;
        W[O_SL + t] = (t < total) ? s_sl[t] : 0;
    }
}

__device__ __forceinline__ bf16x8 cvt8(float4 a, float4 b) {
    bf16x8 r;
    r[0] = (short)f2bf(a.x); r[1] = (short)f2bf(a.y); r[2] = (short)f2bf(a.z); r[3] = (short)f2bf(a.w);
    r[4] = (short)f2bf(b.x); r[5] = (short)f2bf(b.y); r[6] = (short)f2bf(b.z); r[7] = (short)f2bf(b.w);
    return r;
}

// stb = bf16(relu([se|te] @ W_st + b_st)).  LDS-free MFMA, 1 wave/block, 16m x 32n tile.
__global__ __launch_bounds__(64) void k_fc1(const float* __restrict__ se, const float* __restrict__ te,
                                            const ushort* __restrict__ WstT, const float* __restrict__ bias,
                                            ushort* __restrict__ stb) {
    int bid = blockIdx.x;
    int m0 = (bid >> 4) * 16, n0 = (bid & 15) * 32;
    int lane = threadIdx.x;
    int lhi = lane >> 4, llo = lane & 15;
    f32x4 acc[2] = {};
    #pragma unroll
    for (int kk = 0; kk < 20; kk++) {
        int kb = kk * 32 + lhi * 8;
        const float* xr = (kb < 512) ? se + (size_t)(m0 + llo) * 512 + kb
                                     : te + (size_t)(m0 + llo) * 128 + (kb - 512);
        float4 x0 = *(const float4*)xr;
        float4 x1 = *(const float4*)(xr + 4);
        bf16x8 bfr = cvt8(x0, x1);
        #pragma unroll
        for (int nt = 0; nt < 2; nt++) {
            bf16x8 afr = *(const bf16x8*)(WstT + (size_t)(n0 + nt * 16 + llo) * 640 + kb);
            acc[nt] = __builtin_amdgcn_mfma_f32_16x16x32_bf16(afr, bfr, acc[nt], 0, 0, 0);
        }
    }
    #pragma unroll
    for (int nt = 0; nt < 2; nt++) {
        int n = n0 + nt * 16 + lhi * 4;
        float4 bb = *(const float4*)(bias + n);
        ushort4 o;
        o.x = f2bf(fmaxf(acc[nt][0] + bb.x, 0.f));
        o.y = f2bf(fmaxf(acc[nt][1] + bb.y, 0.f));
        o.z = f2bf(fmaxf(acc[nt][2] + bb.z, 0.f));
        o.w = f2bf(fmaxf(acc[nt][3] + bb.w, 0.f));
        *(ushort4*)(stb + (size_t)(m0 + llo) * 512 + n) = o;
    }
}

// LNG = stb @ W_q + b_q (fp32 out).  LDS-free MFMA, 1 wave/block, 16m x 32n tile.
__global__ __launch_bounds__(64) void k_fc2(const ushort* __restrict__ stb, const ushort* __restrict__ WqT,
                                            const float* __restrict__ bias, float* __restrict__ LNG) {
    int n0 = blockIdx.x * 32, m0 = blockIdx.y * 16;
    int lane = threadIdx.x;
    int lhi = lane >> 4, llo = lane & 15;
    f32x4 acc[2] = {};
    #pragma unroll
    for (int kk = 0; kk < 16; kk++) {
        int kb = kk * 32 + lhi * 8;
        bf16x8 bfr = *(const bf16x8*)(stb + (size_t)(m0 + llo) * 512 + kb);
        #pragma unroll
        for (int nt = 0; nt < 2; nt++) {
            int n = n0 + nt * 16 + llo; if (n > 2055) n = 2055;
            bf16x8 afr = *(const bf16x8*)(WqT + (size_t)n * 512 + kb);
            acc[nt] = __builtin_amdgcn_mfma_f32_16x16x32_bf16(afr, bfr, acc[nt], 0, 0, 0);
        }
    }
    #pragma unroll
    for (int nt = 0; nt < 2; nt++) {
        int n = n0 + nt * 16 + lhi * 4;
        if (n < 2056) {
            float4 bb = *(const float4*)(bias + n);
            f32x4 v = {acc[nt][0] + bb.x, acc[nt][1] + bb.y, acc[nt][2] + bb.z, acc[nt][3] + bb.w};
            *(f32x4*)(LNG + (size_t)(m0 + llo) * 2056 + n) = v;
        }
    }
}

// Per active arg t: split LNG row -> GQB(bf16), QLB(bf16 local query), none-logit, QB.
__global__ __launch_bounds__(256) void k_extract(const int* __restrict__ W, const float* __restrict__ LNG,
                                                 const float* __restrict__ bkey,
                                                 ushort* __restrict__ GQB, ushort* __restrict__ QLB,
                                                 float* __restrict__ out, int L, float* __restrict__ QB) {
    int t = blockIdx.x;
    int total = W[O_TOT];
    int tid = threadIdx.x;
    if (t >= total) {
        if (tid < 128) QLB[t * 128 + tid] = 0;
        else GQB[t * 128 + tid - 128] = 0;
        return;
    }
    int b = W[O_AB + t], slot = W[O_SL + t];
    const float* base = LNG + b * LNGW + slot * DIMQ;
    __shared__ float sl[CTXD];
    if (tid < 128) {
        float v = base[tid];
        sl[tid] = v;
        QLB[t * 128 + tid] = f2bf(v);
    } else {
        int d = tid - 128;
        GQB[t * 128 + d] = f2bf(base[129 + d]);
    }
    if (tid == 0) {
        int np = W[O_NP];
        out[np + t] = (float)t;
        out[L + np + t] = base[128];
    }
    __syncthreads();
    if (tid == 0) {
        float qb = 0.f;
        for (int k = 0; k < 128; k++) qb += bkey[k] * sl[k];
        QB[t] = qb;
    }
}

// QK[2048 x 256] = QLB[2048 x 128] @ WKB^T.  LDS-free MFMA, 1 wave/block, 16t x 32v.
__global__ __launch_bounds__(64) void k_qk(const ushort* __restrict__ QLB, const ushort* __restrict__ WKB,
                                           float* __restrict__ QK) {
    int n0 = blockIdx.x * 32, m0 = blockIdx.y * 16;
    int lane = threadIdx.x;
    int lhi = lane >> 4, llo = lane & 15;
    f32x4 acc[2] = {};
    #pragma unroll
    for (int kk = 0; kk < 4; kk++) {
        int kb = kk * 32 + lhi * 8;
        bf16x8 bfr = *(const bf16x8*)(QLB + (size_t)(m0 + llo) * 128 + kb);
        #pragma unroll
        for (int nt = 0; nt < 2; nt++) {
            bf16x8 afr = *(const bf16x8*)(WKB + (size_t)(n0 + nt * 16 + llo) * 128 + kb);
            acc[nt] = __builtin_amdgcn_mfma_f32_16x16x32_bf16(afr, bfr, acc[nt], 0, 0, 0);
        }
    }
    #pragma unroll
    for (int nt = 0; nt < 2; nt++) {
        int v = n0 + nt * 16 + lhi * 4;
        *(f32x4*)(QK + (size_t)(m0 + llo) * 256 + v) = acc[nt];
    }
}

// gather + L2-normalize definition embeddings -> bf16 table in ws
// MUST launch after k_pairs (GKB overlays QK/LNG/WST/WQT — ws contract above).
__global__ __launch_bounds__(256) void k_gk(const int* __restrict__ gctx, const float* __restrict__ emb,
                                            ushort* __restrict__ gkb) {
    int tid = threadIdx.x;
    int g = blockIdx.x * 8 + (tid >> 5);
    int row = gctx[g];
    int c = tid & 31;
    float4 e = *(const float4*)(emb + (size_t)row * 128 + c * 4);
    float ss = e.x * e.x + e.y * e.y + e.z * e.z + e.w * e.w;
    #pragma unroll
    for (int off = 1; off < 32; off <<= 1) ss += __shfl_xor(ss, off);
    float sc = 1.f / (1e-7f + sqrtf(ss));
    ushort4 o;
    o.x = f2bf(e.x * sc); o.y = f2bf(e.y * sc); o.z = f2bf(e.z * sc); o.w = f2bf(e.w * sc);
    *(ushort4*)(gkb + (size_t)g * 128 + c * 4) = o;
}

// local logits: 4-lane groups, 16 rows/wave, QK staged in LDS (broadcast reads).
__global__ __launch_bounds__(256) void k_pairs(const int* __restrict__ W, const float* __restrict__ ctxv,
                                               const float* __restrict__ QK, const float* __restrict__ QB,
                                               float* __restrict__ out, int L) {
    int b = blockIdx.x >> 2, sub = blockIdx.x & 3;
    int as = W[O_AS + b];
    int cnt = W[O_AS + b + 1] - as;
    if (cnt == 0) return;
    int cs = W[O_CS + b];
    int len = W[O_CS + b + 1] - cs;
    int j0 = (len * sub) >> 2, j1 = (len * (sub + 1)) >> 2;
    __shared__ float sqk[MAXA][256];
    __shared__ float sqb[MAXA];
    __shared__ int sps[MAXA];
    int tid = threadIdx.x;
    for (int i = tid; i < cnt * 256; i += 256) sqk[i >> 8][i & 255] = QK[(as + (i >> 8)) * 256 + (i & 255)];
    if (tid < cnt) { sqb[tid] = QB[as + tid]; sps[tid] = W[O_PS + as + tid]; }
    __syncthreads();
    int wv = tid >> 6, lane = tid & 63;
    int g = lane >> 2, il = lane & 3;
    for (int jb = j0 + wv * 16; jb < j1; jb += 64) {
        int j = jb + g;
        bool ok = (j < j1);
        int row = cs + (ok ? j : j1 - 1);
        const float* xr = ctxv + (size_t)row * 256;
        float acc[MAXA] = {};
        #pragma unroll
        for (int c = 0; c < 16; c++) {
            float4 x4 = *(const float4*)(xr + c * 16 + il * 4);
            #pragma unroll
            for (int a = 0; a < MAXA; a++) {
                if (a < cnt) {
                    float4 q4 = *(const float4*)(&sqk[a][c * 16 + il * 4]);
                    acc[a] += x4.x * q4.x + x4.y * q4.y + x4.z * q4.z + x4.w * q4.w;
                }
            }
        }
        #pragma unroll
        for (int a = 0; a < MAXA; a++) {
            if (a < cnt) {
                float p = acc[a];
                p += __shfl_xor(p, 1);
                p += __shfl_xor(p, 2);
                if (il == 0 && ok) {
                    out[sps[a] + j] = (float)(as + a);
                    out[L + sps[a] + j] = p + sqb[a];
                }
            }
        }
    }
}

// global logits via bf16 MFMA (R12/R15/R19 dbuf structure — measured best, 136.7us).
// Block = 128 defs x 256 args, 4 waves x 32 defs; GKB A-frags register-resident;
// GQB B-frags prefetched one 32-arg chunk ahead; double-buffered LDS epilogue,
// one barrier per chunk, 512B-contiguous stores for value+index planes.
// y-tile sweep measured: 4 tiles=143.7us, 8 tiles=136.7us (OPT), 16 tiles=199us.
__global__ __launch_bounds__(256) void k_gglob(const int* __restrict__ W, const ushort* __restrict__ GQB,
                                               const ushort* __restrict__ GKB, float* __restrict__ out, int L) {
    __shared__ float tile[2][32][132];
    int total = W[O_TOT], np = W[O_NP];
    int t0 = blockIdx.y * 256;
    if (t0 >= total) return;
    float* outi = out + np + total;
    float* outv = out + L + np + total;
    int g0 = blockIdx.x * 128;
    int tid = threadIdx.x, wv = tid >> 6, lane = tid & 63;
    int lhi = lane >> 4, llo = lane & 15;
    int gw = wv * 32;
    bf16x8 afr[2][4];
    #pragma unroll
    for (int nt = 0; nt < 2; nt++) {
        int g = g0 + gw + nt * 16 + llo;
        const ushort* ap = GKB + (size_t)(g < DEFN ? g : DEFN - 1) * 128 + lhi * 8;
        #pragma unroll
        for (int kk = 0; kk < 4; kk++)
            afr[nt][kk] = *(const bf16x8*)(ap + kk * 32);
    }
    int nchunk = (total - t0 + 31) >> 5;
    if (nchunk > 8) nchunk = 8;
    bf16x8 bfr[2][4];
    #pragma unroll
    for (int ts = 0; ts < 2; ts++)
        #pragma unroll
        for (int kk = 0; kk < 4; kk++)
            bfr[ts][kk] = *(const bf16x8*)(GQB + (size_t)(t0 + ts * 16 + llo) * 128 + kk * 32 + lhi * 8);
    int half = lane >> 5, cc = (lane & 31) * 4;
    bool gok = (g0 + cc) < DEFN;
    for (int tc = 0; tc < nchunk; tc++) {
        int t1 = t0 + tc * 32;
        int buf = tc & 1;
        f32x4 acc[2][2] = {};
        #pragma unroll
        for (int nt = 0; nt < 2; nt++)
            #pragma unroll
            for (int kk = 0; kk < 4; kk++)
                #pragma unroll
                for (int ts = 0; ts < 2; ts++)
                    acc[ts][nt] = __builtin_amdgcn_mfma_f32_16x16x32_bf16(afr[nt][kk], bfr[ts][kk], acc[ts][nt], 0, 0, 0);
        if (tc + 1 < nchunk) {
            int t2 = t1 + 32;
            #pragma unroll
            for (int ts = 0; ts < 2; ts++)
                #pragma unroll
                for (int kk = 0; kk < 4; kk++)
                    bfr[ts][kk] = *(const bf16x8*)(GQB + (size_t)(t2 + ts * 16 + llo) * 128 + kk * 32 + lhi * 8);
        }
        #pragma unroll
        for (int nt = 0; nt < 2; nt++)
            #pragma unroll
            for (int ts = 0; ts < 2; ts++)
                *(f32x4*)&tile[buf][ts * 16 + llo][gw + nt * 16 + lhi * 4] = acc[ts][nt];
        __syncthreads();
        #pragma unroll
        for (int rp = 0; rp < 4; rp++) {
            int r = wv * 8 + rp * 2 + half;
            int t = t1 + r;
            if (t < total && gok) {
                size_t rb = (size_t)t * DEFN + g0 + cc;
                *(f32x4*)(outv + rb) = *(const f32x4*)&tile[buf][r][cc];
                float ft = (float)t;
                f32x4 fi = {ft, ft, ft, ft};
                *(f32x4*)(outi + rb) = fi;
            }
        }
    }
}

extern "C" void kernel_launch(void* const* d_in, const int* in_sizes, int n_in,
                              void* d_out, int out_size, void* d_ws, size_t ws_size,
                              hipStream_t stream) {
    const float* ctx_vals  = (const float*)d_in[0];
    const float* state_emb = (const float*)d_in[1];
    const float* tactic    = (const float*)d_in[2];
    const float* emb       = (const float*)d_in[3];
    const float* W_key     = (const float*)d_in[4];
    const float* b_key     = (const float*)d_in[5];
    const float* W_st      = (const float*)d_in[6];
    const float* b_st      = (const float*)d_in[7];
    const float* W_q       = (const float*)d_in[8];
    const float* b_q       = (const float*)d_in[9];
    const int* ctx_ids     = (const int*)d_in[10];
    const int* arg_cnt     = (const int*)d_in[11];
    const int* gctx        = (const int*)d_in[12];
    int n_ctx = in_sizes[10];
    int L = out_size / 2;
    int* W  = (int*)d_ws;
    float* F = (float*)d_ws;
    float* out = (float*)d_out;

    k_head<<<dim3(1904), dim3(256), 0, stream>>>(ctx_ids, n_ctx, W,
                                                 W_st, (ushort*)(F + F_WST),
                                                 W_q, (ushort*)(F + F_WQT),
                                                 W_key, (ushort*)(F + F_WKB));
    k_scan<<<dim3(1), dim3(256), 0, stream>>>(arg_cnt, W);
    k_fc1<<<dim3(256), dim3(64), 0, stream>>>(state_emb, tactic, (ushort*)(F + F_WST), b_st,
                                              (ushort*)(F + F_STB));
    k_fc2<<<dim3(65, 16), dim3(64), 0, stream>>>((ushort*)(F + F_STB), (ushort*)(F + F_WQT), b_q,
                                                 F + F_LNG);
    k_extract<<<dim3(2048), dim3(256), 0, stream>>>(W, F + F_LNG, b_key,
                                                    (ushort*)(F + F_GQB), (ushort*)(F + F_QLB),
                                                    out, L, F + F_QB);
    k_qk<<<dim3(8, 128), dim3(64), 0, stream>>>((ushort*)(F + F_QLB), (ushort*)(F + F_WKB), F + F_QK);
    k_pairs<<<dim3(1024), dim3(256), 0, stream>>>(W, ctx_vals, F + F_QK, F + F_QB, out, L);
    k_gk<<<dim3(2500), dim3(256), 0, stream>>>(gctx, emb, (ushort*)(F + F_GKB));
    k_gglob<<<dim3(157, 8), dim3(256), 0, stream>>>(W, (ushort*)(F + F_GQB), (ushort*)(F + F_GKB), out, L);
}